// Round 2
// baseline (142.836 us; speedup 1.0000x reference)
//
#include <hip/hip_runtime.h>
#include <hip/hip_bf16.h>

// KGATPGExp: out[e] = sigmoid( logit(noise[e]) + MLP(concat(emb[col],emb[row],emb[src],emb[dst])) )
// Decomposition:
//   c[64]   = b1 + emb[src]@W1[256:384] + emb[dst]@W1[384:512]          (edge-invariant)
//   F[n][:] = emb[n]@W1[0:128]   + c     (bf16, per node)               (fg_kernel, MFMA)
//   G[n][:] = emb[n]@W1[128:256]         (bf16, per node)
//   out[e]  = sigmoid(logit(noise) + b2 + W2 . relu(F[col[e]] + G[row[e]]))   (edge_kernel)
// This turns 26 GFLOP of per-edge fp32 MLP into 3.3 GFLOP of bf16 MFMA over nodes
// + a 256 B/edge gather.

typedef __bf16 bf16x8 __attribute__((ext_vector_type(8)));
typedef float  f32x16 __attribute__((ext_vector_type(16)));
typedef unsigned short u16;

#define W1T_LDS_STRIDE 264   // 256 + 8 pad: breaks power-of-2 row stride for b128 reads
#define Z16 {0.f,0.f,0.f,0.f,0.f,0.f,0.f,0.f,0.f,0.f,0.f,0.f,0.f,0.f,0.f,0.f}

__device__ __forceinline__ unsigned bfbits(float f){       // fp32 -> bf16 bits, RNE
  unsigned u = __builtin_bit_cast(unsigned, f);
  return (u + 0x7fffu + ((u >> 16) & 1u)) >> 16;
}
__device__ __forceinline__ unsigned pk2(float a, float b){ // pack 2 fp32 -> bf16x2 bits
  return bfbits(a) | (bfbits(b) << 16);
}
__device__ __forceinline__ float bflo(unsigned u){ return __builtin_bit_cast(float, u << 16); }
__device__ __forceinline__ float bfhi(unsigned u){ return __builtin_bit_cast(float, u & 0xffff0000u); }

// ---------------------------------------------------------------------------
// prep: blocks 0..63 transpose W1[0:256][0:64] -> w1t[64][256] bf16 (for MFMA B reads);
//       block 64 computes c[64] in fp32.
__global__ void prep_kernel(const float* __restrict__ embed, const float* __restrict__ W1,
                            const float* __restrict__ b1, const int* __restrict__ srcp,
                            const int* __restrict__ dstp, float* __restrict__ c_ws,
                            u16* __restrict__ w1t)
{
  int b = blockIdx.x, tid = threadIdx.x;
  if (b == 64){
    if (tid < 64){
      int si = srcp[0], di = dstp[0];
      const float* se = embed + (size_t)si * 128;
      const float* de = embed + (size_t)di * 128;
      float acc = b1[tid];
      #pragma unroll 4
      for (int k = 0; k < 128; ++k){
        acc += se[k] * W1[(256 + k) * 64 + tid];
        acc += de[k] * W1[(384 + k) * 64 + tid];
      }
      c_ws[tid] = acc;
    }
    return;
  }
  int n = tid & 63;
  int k = b * 4 + (tid >> 6);          // 64 blocks x 4 k each = k 0..255, coalesced in n
  w1t[n * 256 + k] = (u16)bfbits(W1[k * 64 + n]);
}

// ---------------------------------------------------------------------------
// fg: F = emb@W1a + c, G = emb@W1b over 100K nodes. One 32-node tile per wave.
//   A (emb rows, gathered streaming): lane holds A[m=lane&31][k=(lane>>5)*8+j]
//   B (W1T from LDS):                 lane holds B[k=(lane>>5)*8+j][n=lane&31]
//   C/D:                              col(n)=lane&31, row(m)=(r&3)+8*(r>>2)+4*(lane>>5)
__global__ __launch_bounds__(256, 3) void fg_kernel(
    const float* __restrict__ embed, const u16* __restrict__ w1t,
    const float* __restrict__ c_ws, u16* __restrict__ F, u16* __restrict__ G, int NN)
{
  __shared__ __align__(16) u16 sW[64 * W1T_LDS_STRIDE];
  __shared__ float sC[64];
  int tid = threadIdx.x;
  for (int i = tid; i < 2048; i += 256){          // 16384 bf16 = 2048 uint4
    uint4 v = ((const uint4*)w1t)[i];
    int e0 = i * 8, n = e0 >> 8, kk = e0 & 255;
    *(uint4*)&sW[n * W1T_LDS_STRIDE + kk] = v;
  }
  if (tid < 64) sC[tid] = c_ws[tid];
  __syncthreads();
  int lane = tid & 63, wave = tid >> 6;
  int nl = lane & 31, h5 = lane >> 5;
  int tile = blockIdx.x * 128 + wave * 32;        // NN % 32 == 0 for this problem
  if (tile >= NN) return;
  const float* erow = embed + (size_t)(tile + nl) * 128;
  f32x16 aF0 = Z16, aF1 = Z16, aG0 = Z16, aG1 = Z16;
  const u16* sw0 = sW + nl * W1T_LDS_STRIDE;          // hidden rows 0..31
  const u16* sw1 = sW + (32 + nl) * W1T_LDS_STRIDE;   // hidden rows 32..63
  #pragma unroll
  for (int s = 0; s < 8; ++s){                    // K = 128, 16 per MFMA
    int ko = s * 16 + h5 * 8;
    float4 x = *(const float4*)(erow + ko);
    float4 y = *(const float4*)(erow + ko + 4);
    uint4 u; u.x = pk2(x.x,x.y); u.y = pk2(x.z,x.w); u.z = pk2(y.x,y.y); u.w = pk2(y.z,y.w);
    bf16x8 a = __builtin_bit_cast(bf16x8, u);
    bf16x8 bF0 = *(const bf16x8*)(sw0 + ko);
    bf16x8 bF1 = *(const bf16x8*)(sw1 + ko);
    bf16x8 bG0 = *(const bf16x8*)(sw0 + 128 + ko);   // W1b lives at k=128..255 of w1t
    bf16x8 bG1 = *(const bf16x8*)(sw1 + 128 + ko);
    aF0 = __builtin_amdgcn_mfma_f32_32x32x16_bf16(a, bF0, aF0, 0, 0, 0);
    aF1 = __builtin_amdgcn_mfma_f32_32x32x16_bf16(a, bF1, aF1, 0, 0, 0);
    aG0 = __builtin_amdgcn_mfma_f32_32x32x16_bf16(a, bG0, aG0, 0, 0, 0);
    aG1 = __builtin_amdgcn_mfma_f32_32x32x16_bf16(a, bG1, aG1, 0, 0, 0);
  }
  float cv0 = sC[nl], cv1 = sC[32 + nl];
  #pragma unroll
  for (int r = 0; r < 16; ++r){
    int node = tile + (r & 3) + 8 * (r >> 2) + 4 * h5;
    u16* fr = F + (size_t)node * 64 + nl;
    u16* gr = G + (size_t)node * 64 + nl;
    fr[0]  = (u16)bfbits(aF0[r] + cv0);   // fold c into F
    fr[32] = (u16)bfbits(aF1[r] + cv1);
    gr[0]  = (u16)bfbits(aG0[r]);
    gr[32] = (u16)bfbits(aG1[r]);
  }
}

// ---------------------------------------------------------------------------
// edge: 8 lanes per edge, lane j handles hidden [8j,8j+8) as one uint4 (16 B) gather.
// Per wave: 8 edges per iteration, 64 edges total per wave; 256 edges per block.
__global__ __launch_bounds__(256, 8) void edge_kernel(
    const u16* __restrict__ F, const u16* __restrict__ G,
    const float* __restrict__ W2, const float* __restrict__ b2,
    const float* __restrict__ noise, const int* __restrict__ col,
    const int* __restrict__ row, float* __restrict__ out, int E)
{
  int tid = threadIdx.x;
  int lane = tid & 63, wave = tid >> 6;
  int j = lane & 7, grp = lane >> 3;
  float4 w2a = ((const float4*)W2)[2 * j];
  float4 w2b = ((const float4*)W2)[2 * j + 1];
  float b2v = b2[0];
  int base = blockIdx.x * 256 + wave * 64;
  #pragma unroll 2
  for (int it = 0; it < 8; ++it){
    int e0 = base + it * 8;
    if (e0 >= E) break;                 // wave-uniform (E % 8 == 0)
    int e = e0 + grp;
    int ci = col[e], ri = row[e];
    uint4 fv = ((const uint4*)(F + (size_t)ci * 64))[j];
    uint4 gv = ((const uint4*)(G + (size_t)ri * 64))[j];
    float p = 0.f, h;
    h = fmaxf(bflo(fv.x) + bflo(gv.x), 0.f); p += h * w2a.x;
    h = fmaxf(bfhi(fv.x) + bfhi(gv.x), 0.f); p += h * w2a.y;
    h = fmaxf(bflo(fv.y) + bflo(gv.y), 0.f); p += h * w2a.z;
    h = fmaxf(bfhi(fv.y) + bfhi(gv.y), 0.f); p += h * w2a.w;
    h = fmaxf(bflo(fv.z) + bflo(gv.z), 0.f); p += h * w2b.x;
    h = fmaxf(bfhi(fv.z) + bfhi(gv.z), 0.f); p += h * w2b.y;
    h = fmaxf(bflo(fv.w) + bflo(gv.w), 0.f); p += h * w2b.z;
    h = fmaxf(bfhi(fv.w) + bfhi(gv.w), 0.f); p += h * w2b.w;
    p += __shfl_xor(p, 1, 64);
    p += __shfl_xor(p, 2, 64);
    p += __shfl_xor(p, 4, 64);
    if (j == 0){
      float ns = noise[e];
      float g = logf(ns) - log1pf(-ns) + p + b2v;
      out[e] = 1.f / (1.f + expf(-g));
    }
  }
}

// ---------------------------------------------------------------------------
// Insurance path if ws_size is too small for F/G tables: correct-but-slow fp32.
__global__ void naive_kernel(const float* __restrict__ embed, const float* __restrict__ W1,
    const float* __restrict__ b1, const float* __restrict__ W2, const float* __restrict__ b2,
    const float* __restrict__ noise, const int* __restrict__ col, const int* __restrict__ row,
    const int* __restrict__ srcp, const int* __restrict__ dstp, float* __restrict__ out, int E)
{
  int e = blockIdx.x * 256 + threadIdx.x;
  if (e >= E) return;
  int ci = col[e], ri = row[e], si = srcp[0], di = dstp[0];
  const float* ce = embed + (size_t)ci * 128;
  const float* re = embed + (size_t)ri * 128;
  const float* se = embed + (size_t)si * 128;
  const float* de = embed + (size_t)di * 128;
  float w = b2[0];
  for (int jj = 0; jj < 64; ++jj){
    float hh = b1[jj];
    for (int k = 0; k < 128; ++k){
      hh += ce[k] * W1[k * 64 + jj] + re[k] * W1[(128 + k) * 64 + jj]
          + se[k] * W1[(256 + k) * 64 + jj] + de[k] * W1[(384 + k) * 64 + jj];
    }
    w += fmaxf(hh, 0.f) * W2[jj];
  }
  float ns = noise[e];
  float g = logf(ns) - log1pf(-ns) + w;
  out[e] = 1.f / (1.f + expf(-g));
}

// ---------------------------------------------------------------------------
extern "C" void kernel_launch(void* const* d_in, const int* in_sizes, int n_in,
                              void* d_out, int out_size, void* d_ws, size_t ws_size,
                              hipStream_t stream)
{
  const float* embed = (const float*)d_in[0];
  const float* W1    = (const float*)d_in[1];
  const float* b1    = (const float*)d_in[2];
  const float* W2    = (const float*)d_in[3];
  const float* b2    = (const float*)d_in[4];
  const float* noise = (const float*)d_in[5];
  const int*   col   = (const int*)d_in[6];
  const int*   rowp  = (const int*)d_in[7];
  const int*   srcp  = (const int*)d_in[8];
  const int*   dstp  = (const int*)d_in[9];
  const int E  = in_sizes[5];
  const int NN = in_sizes[0] / 128;
  float* out = (float*)d_out;

  // ws layout: [0,256) c[64] fp32 | [256, 33024) w1t bf16 [64][256] | F bf16 | G bf16
  const size_t fOff   = 33280;                        // 16B-aligned
  const size_t fBytes = (size_t)NN * 64 * sizeof(u16);
  const size_t need   = fOff + 2 * fBytes;

  if (ws_size >= need){
    float* c_ws = (float*)d_ws;
    u16*   w1t  = (u16*)((char*)d_ws + 256);
    u16*   F    = (u16*)((char*)d_ws + fOff);
    u16*   G    = (u16*)((char*)d_ws + fOff + fBytes);
    prep_kernel<<<65, 256, 0, stream>>>(embed, W1, b1, srcp, dstp, c_ws, w1t);
    fg_kernel<<<(NN + 127) / 128, 256, 0, stream>>>(embed, w1t, c_ws, F, G, NN);
    edge_kernel<<<(E + 255) / 256, 256, 0, stream>>>(F, G, W2, b2, noise, col, rowp, out, E);
  } else {
    naive_kernel<<<(E + 255) / 256, 256, 0, stream>>>(embed, W1, b1, W2, b2, noise,
                                                      col, rowp, srcp, dstp, out, E);
  }
}

// Round 3
// 133.976 us; speedup vs baseline: 1.0661x; 1.0661x over previous
//
#include <hip/hip_runtime.h>
#include <hip/hip_bf16.h>

// KGATPGExp: out[e] = sigmoid( logit(noise[e]) + MLP(concat(emb[col],emb[row],emb[src],emb[dst])) )
// Decomposition (validated R2, absmax 3.9e-3 vs thr 2e-2):
//   c[64]   = b1 + emb[src]@W1[256:384] + emb[dst]@W1[384:512]          (edge-invariant)
//   F[n][:] = emb[n]@W1[0:128] + c       (bf16, per node)   } fg_kernel (MFMA, HBM-bound)
//   G[n][:] = emb[n]@W1[128:256]         (bf16, per node)   }
//   out[e]  = sigmoid(logit(noise) + b2 + W2 . relu(F[col[e]] + G[row[e]]))   (edge_kernel)
// R3: prep folded into fg (W1 transpose + c computed per-block from L2-hot W1);
//     edge restructured to 1 octet/wave (8x waves -> 8x outstanding gathers).

typedef __bf16 bf16x8 __attribute__((ext_vector_type(8)));
typedef float  f32x16 __attribute__((ext_vector_type(16)));
typedef unsigned short u16;

#define WSTR 264   // sW row stride (u16): 256 + 8 pad
#define Z16 {0.f,0.f,0.f,0.f,0.f,0.f,0.f,0.f,0.f,0.f,0.f,0.f,0.f,0.f,0.f,0.f}

__device__ __forceinline__ unsigned bfbits(float f){       // fp32 -> bf16 bits, RNE
  unsigned u = __builtin_bit_cast(unsigned, f);
  return (u + 0x7fffu + ((u >> 16) & 1u)) >> 16;
}
__device__ __forceinline__ unsigned pk2(float a, float b){ // pack 2 fp32 -> bf16x2 bits
  return bfbits(a) | (bfbits(b) << 16);
}
__device__ __forceinline__ float bflo(unsigned u){ return __builtin_bit_cast(float, u << 16); }
__device__ __forceinline__ float bfhi(unsigned u){ return __builtin_bit_cast(float, u & 0xffff0000u); }

// ---------------------------------------------------------------------------
// fg: F = emb@W1a + c, G = emb@W1b over all nodes. One 32-node tile per wave,
// 4 waves (128 nodes) per block. Per-block prologue builds the bf16 transposed
// W1[0:256] in LDS and the c vector (both from L2-hot W1).
//   A (emb rows, streamed):  lane holds A[m=lane&31][k=(lane>>5)*8+j]
//   B (sW from LDS):         lane holds B[k=(lane>>5)*8+j][n=lane&31]
//   C/D:                     col(n)=lane&31, row(m)=(r&3)+8*(r>>2)+4*(lane>>5)
__global__ __launch_bounds__(256, 3) void fg_kernel(
    const float* __restrict__ embed, const float* __restrict__ W1,
    const float* __restrict__ b1, const int* __restrict__ srcp,
    const int* __restrict__ dstp, u16* __restrict__ F, u16* __restrict__ G, int NN)
{
  __shared__ __align__(16) u16 sW[64 * WSTR];
  __shared__ float sC[64];
  __shared__ float sRed[256];
  int tid = threadIdx.x;

  // --- prologue A: transpose W1[0:256][0:64] fp32 -> sW[n][k] bf16 ---
  #pragma unroll
  for (int i = 0; i < 16; ++i){
    int idx = i * 256 + tid;               // 4096 float4 reads, fully coalesced
    int k = idx >> 4, q = idx & 15;
    float4 v = *(const float4*)(W1 + k * 64 + q * 4);
    sW[(4*q+0) * WSTR + k] = (u16)bfbits(v.x);
    sW[(4*q+1) * WSTR + k] = (u16)bfbits(v.y);
    sW[(4*q+2) * WSTR + k] = (u16)bfbits(v.z);
    sW[(4*q+3) * WSTR + k] = (u16)bfbits(v.w);
  }
  // --- prologue B: c partials, 4-way k-split across the block ---
  {
    int h = tid & 63, part = tid >> 6;
    int si = srcp[0], di = dstp[0];
    const float* se  = embed + (size_t)si * 128 + part * 32;
    const float* de  = embed + (size_t)di * 128 + part * 32;
    const float* w1s = W1 + (256 + part * 32) * 64 + h;
    const float* w1d = W1 + (384 + part * 32) * 64 + h;
    float acc = 0.f;
    #pragma unroll 8
    for (int k = 0; k < 32; ++k){
      acc += se[k] * w1s[k * 64];
      acc += de[k] * w1d[k * 64];
    }
    sRed[tid] = acc;
  }
  __syncthreads();
  if (tid < 64) sC[tid] = b1[tid] + sRed[tid] + sRed[64+tid] + sRed[128+tid] + sRed[192+tid];
  __syncthreads();

  // --- main MFMA loop ---
  int lane = tid & 63, wave = tid >> 6;
  int nl = lane & 31, h5 = lane >> 5;
  int tile = blockIdx.x * 128 + wave * 32;
  if (tile >= NN) return;                      // NN % 32 == 0; barriers already passed
  const float* erow = embed + (size_t)(tile + nl) * 128;
  f32x16 aF0 = Z16, aF1 = Z16, aG0 = Z16, aG1 = Z16;
  const u16* sw0 = sW + nl * WSTR;             // hidden rows 0..31
  const u16* sw1 = sW + (32 + nl) * WSTR;      // hidden rows 32..63
  #pragma unroll
  for (int s = 0; s < 8; ++s){                 // K = 128, 16 per MFMA
    int ko = s * 16 + h5 * 8;
    float4 x = *(const float4*)(erow + ko);
    float4 y = *(const float4*)(erow + ko + 4);
    uint4 u; u.x = pk2(x.x,x.y); u.y = pk2(x.z,x.w); u.z = pk2(y.x,y.y); u.w = pk2(y.z,y.w);
    bf16x8 a = __builtin_bit_cast(bf16x8, u);
    bf16x8 bF0 = *(const bf16x8*)(sw0 + ko);
    bf16x8 bF1 = *(const bf16x8*)(sw1 + ko);
    bf16x8 bG0 = *(const bf16x8*)(sw0 + 128 + ko);   // W1b at k=128..255
    bf16x8 bG1 = *(const bf16x8*)(sw1 + 128 + ko);
    aF0 = __builtin_amdgcn_mfma_f32_32x32x16_bf16(a, bF0, aF0, 0, 0, 0);
    aF1 = __builtin_amdgcn_mfma_f32_32x32x16_bf16(a, bF1, aF1, 0, 0, 0);
    aG0 = __builtin_amdgcn_mfma_f32_32x32x16_bf16(a, bG0, aG0, 0, 0, 0);
    aG1 = __builtin_amdgcn_mfma_f32_32x32x16_bf16(a, bG1, aG1, 0, 0, 0);
  }
  float cv0 = sC[nl], cv1 = sC[32 + nl];
  #pragma unroll
  for (int r = 0; r < 16; ++r){
    int node = tile + (r & 3) + 8 * (r >> 2) + 4 * h5;
    u16* fr = F + (size_t)node * 64 + nl;
    u16* gr = G + (size_t)node * 64 + nl;
    fr[0]  = (u16)bfbits(aF0[r] + cv0);        // fold c into F
    fr[32] = (u16)bfbits(aF1[r] + cv1);
    gr[0]  = (u16)bfbits(aG0[r]);
    gr[32] = (u16)bfbits(aG1[r]);
  }
}

// ---------------------------------------------------------------------------
// edge: 8 lanes per edge, lane j handles hidden [8j,8j+8) as one 16 B gather.
// One edge-octet per wave (no loop): max outstanding gathers per SIMD.
__global__ __launch_bounds__(256, 8) void edge_kernel(
    const u16* __restrict__ F, const u16* __restrict__ G,
    const float* __restrict__ W2, const float* __restrict__ b2,
    const float* __restrict__ noise, const int* __restrict__ col,
    const int* __restrict__ row, float* __restrict__ out, int E)
{
  int tid = threadIdx.x;
  int lane = tid & 63, wave = tid >> 6;
  int j = lane & 7, grp = lane >> 3;
  int e0 = blockIdx.x * 32 + wave * 8;
  if (e0 >= E) return;                         // wave-uniform
  int e = e0 + grp; if (e >= E) e = E - 1;     // clamp (safe read), store masked below
  int ci = col[e], ri = row[e];
  uint4 fv = ((const uint4*)(F + (size_t)ci * 64))[j];
  uint4 gv = ((const uint4*)(G + (size_t)ri * 64))[j];
  float4 w2a = ((const float4*)W2)[2 * j];
  float4 w2b = ((const float4*)W2)[2 * j + 1];
  float p = 0.f, h;
  h = fmaxf(bflo(fv.x) + bflo(gv.x), 0.f); p += h * w2a.x;
  h = fmaxf(bfhi(fv.x) + bfhi(gv.x), 0.f); p += h * w2a.y;
  h = fmaxf(bflo(fv.y) + bflo(gv.y), 0.f); p += h * w2a.z;
  h = fmaxf(bfhi(fv.y) + bfhi(gv.y), 0.f); p += h * w2a.w;
  h = fmaxf(bflo(fv.z) + bflo(gv.z), 0.f); p += h * w2b.x;
  h = fmaxf(bfhi(fv.z) + bfhi(gv.z), 0.f); p += h * w2b.y;
  h = fmaxf(bflo(fv.w) + bflo(gv.w), 0.f); p += h * w2b.z;
  h = fmaxf(bfhi(fv.w) + bfhi(gv.w), 0.f); p += h * w2b.w;
  p += __shfl_xor(p, 1, 64);
  p += __shfl_xor(p, 2, 64);
  p += __shfl_xor(p, 4, 64);
  if (j == 0 && e0 + grp < E){
    float ns = noise[e];
    float g = logf(ns) - log1pf(-ns) + p + b2[0];
    out[e] = 1.f / (1.f + expf(-g));
  }
}

// ---------------------------------------------------------------------------
// Insurance path if ws_size is too small for F/G tables: correct-but-slow fp32.
__global__ void naive_kernel(const float* __restrict__ embed, const float* __restrict__ W1,
    const float* __restrict__ b1, const float* __restrict__ W2, const float* __restrict__ b2,
    const float* __restrict__ noise, const int* __restrict__ col, const int* __restrict__ row,
    const int* __restrict__ srcp, const int* __restrict__ dstp, float* __restrict__ out, int E)
{
  int e = blockIdx.x * 256 + threadIdx.x;
  if (e >= E) return;
  int ci = col[e], ri = row[e], si = srcp[0], di = dstp[0];
  const float* ce = embed + (size_t)ci * 128;
  const float* re = embed + (size_t)ri * 128;
  const float* se = embed + (size_t)si * 128;
  const float* de = embed + (size_t)di * 128;
  float w = b2[0];
  for (int jj = 0; jj < 64; ++jj){
    float hh = b1[jj];
    for (int k = 0; k < 128; ++k){
      hh += ce[k] * W1[k * 64 + jj] + re[k] * W1[(128 + k) * 64 + jj]
          + se[k] * W1[(256 + k) * 64 + jj] + de[k] * W1[(384 + k) * 64 + jj];
    }
    w += fmaxf(hh, 0.f) * W2[jj];
  }
  float ns = noise[e];
  float g = logf(ns) - log1pf(-ns) + w;
  out[e] = 1.f / (1.f + expf(-g));
}

// ---------------------------------------------------------------------------
extern "C" void kernel_launch(void* const* d_in, const int* in_sizes, int n_in,
                              void* d_out, int out_size, void* d_ws, size_t ws_size,
                              hipStream_t stream)
{
  const float* embed = (const float*)d_in[0];
  const float* W1    = (const float*)d_in[1];
  const float* b1    = (const float*)d_in[2];
  const float* W2    = (const float*)d_in[3];
  const float* b2    = (const float*)d_in[4];
  const float* noise = (const float*)d_in[5];
  const int*   col   = (const int*)d_in[6];
  const int*   rowp  = (const int*)d_in[7];
  const int*   srcp  = (const int*)d_in[8];
  const int*   dstp  = (const int*)d_in[9];
  const int E  = in_sizes[5];
  const int NN = in_sizes[0] / 128;
  float* out = (float*)d_out;

  const size_t fBytes = (size_t)NN * 64 * sizeof(u16);
  if (ws_size >= 2 * fBytes){
    u16* F = (u16*)d_ws;
    u16* G = (u16*)((char*)d_ws + fBytes);
    fg_kernel<<<(NN + 127) / 128, 256, 0, stream>>>(embed, W1, b1, srcp, dstp, F, G, NN);
    edge_kernel<<<(E + 31) / 32, 256, 0, stream>>>(F, G, W2, b2, noise, col, rowp, out, E);
  } else {
    naive_kernel<<<(E + 255) / 256, 256, 0, stream>>>(embed, W1, b1, W2, b2, noise,
                                                      col, rowp, srcp, dstp, out, E);
  }
}